// Round 14
// baseline (60.556 us; speedup 1.0000x reference)
//
#include <hip/hip_runtime.h>
#include <hip/hip_bf16.h>
#include <cstdint>

typedef __bf16 bf16x8 __attribute__((ext_vector_type(8)));
typedef float  f32x4  __attribute__((ext_vector_type(4)));

constexpr int RTOT  = 2304;          // 9 taps * 256 channels, r = k*256 + c
constexpr int NITER = 36;            // BK = 64 per iteration

#define WAITV8    asm volatile("s_waitcnt vmcnt(8)" ::: "memory")
#define WAITV4    asm volatile("s_waitcnt vmcnt(4)" ::: "memory")
#define WAITV0    asm volatile("s_waitcnt vmcnt(0)" ::: "memory")
#define WAITLGKM0 asm volatile("s_waitcnt lgkmcnt(0)" ::: "memory")
#define SCHEDB    __builtin_amdgcn_sched_barrier(0)

__device__ __forceinline__ float c2f(unsigned w, int hi) {
    union { unsigned u; float f; } v;
    v.u = hi ? (w & 0xffff0000u) : (w << 16);
    return v.f;
}

// ---- prep 1: x [4,256,64,64] f32 (NCHW) -> xh [4,64,64,256] bf16 (NHWC) ----
__global__ __launch_bounds__(256)
void nchw_to_nhwc_bf16(const float* __restrict__ x, __bf16* __restrict__ xh) {
    __shared__ unsigned short tile[256][70];
    const int tid = threadIdx.x;
    const int b = blockIdx.x >> 6;
    const int y = blockIdx.x & 63;
    const float* xp = x + (size_t)b * (256 * 4096) + y * 64;
    #pragma unroll 4
    for (int it = 0; it < 64; ++it) {
        const int ci = it * 4 + (tid >> 6);
        const int xi = tid & 63;
        __bf16 h = (__bf16)xp[(size_t)ci * 4096 + xi];
        tile[ci][xi] = *reinterpret_cast<unsigned short*>(&h);
    }
    __syncthreads();
    unsigned short* op = reinterpret_cast<unsigned short*>(xh) + ((size_t)b * 64 + y) * 64 * 256;
    #pragma unroll 4
    for (int it = 0; it < 64; ++it)
        op[(size_t)it * 256 + tid] = tile[tid][it];
}

// ---- prep 2: w [co][c][k] f32 -> wq, pre-permuted per-lane MFMA B fragments ----
// Fragment (i, wv, f), f = half*2 + nf: lane l holds 8 weights
//   co = wv*32 + nf*16 + (l&15), r = i*64 + half*32 + (l>>4)*8 + j  (r = k*256+c).
// Byte address: (i*8 + wv)*4096 + f*1024 + l*16.
__global__ __launch_bounds__(256)
void weight_prep_frag(const float* __restrict__ w, __bf16* __restrict__ wq) {
    const int e = blockIdx.x * 256 + threadIdx.x;   // 73728 fragment-lanes
    const int l  = e & 63;
    const int f  = (e >> 6) & 3;
    const int wv = (e >> 8) & 7;
    const int i  = e >> 11;
    const int nf = f & 1, half = f >> 1;
    const int co = wv * 32 + nf * 16 + (l & 15);
    const int rb = i * 64 + half * 32 + ((l >> 4) << 3);
    union { ushort4 u2[2]; __bf16 h[8]; } pk;
    #pragma unroll
    for (int j = 0; j < 8; ++j) {
        const int r = rb + j;
        const int c = r & 255, k = r >> 8;
        pk.h[j] = (__bf16)w[co * 2304 + c * 9 + k];
    }
    unsigned short* dst = reinterpret_cast<unsigned short*>(wq) + (size_t)e * 8;
    *reinterpret_cast<ushort4*>(dst)     = pk.u2[0];
    *reinterpret_cast<ushort4*>(dst + 4) = pk.u2[1];
}

// ---- main: fused deformable implicit GEMM, BK=64, A-only LDS, B L2->reg ----
// Block = 32 wo x 256 co, 512 threads / 8 waves (1M x 8N); wave slab 32(M) x 32(N).
// Grid = 512 -> 2 blocks/CU (M-split: A work fully partitioned, only B reg-loads
// duplicated) = 4 waves/SIMD in TWO independent barrier domains.
// Per iter per wave: 4 ds_read_b128 (A) + 4 B reg-loads + 4 A-gathers (uint2)
// + 8 MFMA. Wait ladder (FIFO: B(i+1)@s2, A(i+2)@s5): WAITV8 pre-MFMA0 drains
// B(i) (1 iter old); WAITV4 at combine drains A(i+1) (1 iter old), keeps B(i+1);
// pre-barrier lgkmcnt(0) only -- B(i+1)+A(i+2) cross the barrier.
__global__ __launch_bounds__(512, 4)
void deform_gemm_nhwc(const float* __restrict__ off, const __bf16* __restrict__ xh,
                      const __bf16* __restrict__ wq, float* __restrict__ out) {
    __shared__ float4 s_w[32 * 9];
    __shared__ int4   s_a[32 * 9];
    __shared__ unsigned short sA[2][32 * 64];    // [buf][p*64 + ch], XOR-swizzled

    const int tid  = threadIdx.x;
    const int lane = tid & 63;
    const int wv   = tid >> 6;               // 0..7 = N-eighth
    const int fr   = lane & 15;
    const int fq   = lane >> 4;

    const int bs  = ((blockIdx.x & 7) << 6) | (blockIdx.x >> 3);  // bijective XCD swizzle
    const int b   = bs >> 7;
    const int ho  = (bs >> 1) & 63;
    const int wo0 = (bs & 1) << 5;

    // ---- per-(k, p) bilinear metadata (9 taps x 32 positions) ----
    if (tid < 288) {
        const int i = tid;
        const int k = i >> 5, p = i & 31, wo = wo0 + p;
        const int kh = k / 3, kw = k - kh * 3;
        const float dy = off[(((b * 18) + 2 * k    ) * 64 + ho) * 64 + wo];
        const float dx = off[(((b * 18) + 2 * k + 1) * 64 + ho) * 64 + wo];
        const float sy = (float)(ho - 1 + kh) + dy;
        const float sx = (float)(wo - 1 + kw) + dx;
        const float y0f = floorf(sy), x0f = floorf(sx);
        const float fy = sy - y0f, fx = sx - x0f;
        const int y0 = (int)y0f, x0 = (int)x0f;
        const int y1 = y0 + 1, x1 = x0 + 1;
        const bool vy0 = (unsigned)y0 < 64u, vy1 = (unsigned)y1 < 64u;
        const bool vx0 = (unsigned)x0 < 64u, vx1 = (unsigned)x1 < 64u;
        const int y0c = min(max(y0, 0), 63), y1c = min(max(y1, 0), 63);
        const int x0c = min(max(x0, 0), 63), x1c = min(max(x1, 0), 63);
        float4 wt;
        wt.x = (1.f - fy) * (1.f - fx) * ((vy0 & vx0) ? 1.f : 0.f);
        wt.y = (1.f - fy) * fx         * ((vy0 & vx1) ? 1.f : 0.f);
        wt.z = fy * (1.f - fx)         * ((vy1 & vx0) ? 1.f : 0.f);
        wt.w = fy * fx                 * ((vy1 & vx1) ? 1.f : 0.f);
        s_w[i] = wt;
        s_a[i] = make_int4((y0c << 6) + x0c, (y0c << 6) + x1c,
                           (y1c << 6) + x0c, (y1c << 6) + x1c);
    }

    f32x4 acc[2][2];
    #pragma unroll
    for (int mf = 0; mf < 2; ++mf)
        #pragma unroll
        for (int nf = 0; nf < 2; ++nf)
            acc[mf][nf] = (f32x4){0.f, 0.f, 0.f, 0.f};

    const __bf16* xb = xh + ((size_t)b << 20);
    // A-gen: 512 threads = 32 positions x 16 channel-quads (4 ch / thread / iter)
    const int p    = tid >> 4;               // 0..31
    const int quad = tid & 15;               // c = quad*4 within the 64-ch iter block
    const int aw_off = (p << 6) + ((((quad >> 1) ^ (p & 7))) << 3) + ((quad & 1) << 2);
    const char* base_lane = (const char*)xb + (quad << 3);

    // B fragment source for this wave: iter i frag f at i*32768 + wv*4096 + f*1024 + lane*16
    const char* wqw = (const char*)wq + ((size_t)wv << 12) + (lane << 4);

    // A fragment read offsets (swizzled 16B units) for K32 halves
    const int ua0 = ((0 + fq) ^ (fr & 7)) << 3;
    const int ua1 = ((4 + fq) ^ (fr & 7)) << 3;

    __syncthreads();  // meta ready

    float4 wt_k;
    uint2 ga0, ga1, ga2, ga3;
    const char *aK0, *aK1, *aK2, *aK3;
    bf16x8 br[2][4];                         // B reg double buffer (static idx under unroll)

    {   // tap 0 meta
        wt_k = s_w[p];
        const int4 sa = s_a[p];
        aK0 = base_lane + ((size_t)sa.x << 9);
        aK1 = base_lane + ((size_t)sa.y << 9);
        aK2 = base_lane + ((size_t)sa.z << 9);
        aK3 = base_lane + ((size_t)sa.w << 9);
    }

    // ---- prologue: load B(0); gather+combine A(0); issue A(1) ----
    {
        #pragma unroll
        for (int f = 0; f < 4; ++f)
            br[0][f] = *reinterpret_cast<const bf16x8*>(wqw + f * 1024);
        ga0 = *reinterpret_cast<const uint2*>(aK0);
        ga1 = *reinterpret_cast<const uint2*>(aK1);
        ga2 = *reinterpret_cast<const uint2*>(aK2);
        ga3 = *reinterpret_cast<const uint2*>(aK3);
        WAITV0;
        {
            union { ushort4 u; __bf16 h[4]; } pk;
            #pragma unroll
            for (int j = 0; j < 4; ++j) {
                const unsigned u0 = (j & 2) ? ga0.y : ga0.x, u1 = (j & 2) ? ga1.y : ga1.x;
                const unsigned u2 = (j & 2) ? ga2.y : ga2.x, u3 = (j & 2) ? ga3.y : ga3.x;
                pk.h[j] = (__bf16)(wt_k.x * c2f(u0, j & 1) + wt_k.y * c2f(u1, j & 1)
                                 + wt_k.z * c2f(u2, j & 1) + wt_k.w * c2f(u3, j & 1));
            }
            *reinterpret_cast<ushort4*>(&sA[0][aw_off]) = pk.u;
        }
        // issue A(1): same tap, channel block 1 (byte offset 128)
        ga0 = *reinterpret_cast<const uint2*>(aK0 + 128);
        ga1 = *reinterpret_cast<const uint2*>(aK1 + 128);
        ga2 = *reinterpret_cast<const uint2*>(aK2 + 128);
        ga3 = *reinterpret_cast<const uint2*>(aK3 + 128);
        SCHEDB;
        WAITLGKM0;
        __builtin_amdgcn_s_barrier();
        SCHEDB;
    }

    // ---- main loop: 36 iterations of BK=64 ----
    #pragma unroll 4
    for (int i = 0; i < NITER; ++i) {
        const unsigned short* sAc = sA[i & 1];

        // 1) A fragment reads (4 x ds_read_b128; rows mf*16+fr, two K-halves)
        bf16x8 a0[2], a1[2];
        #pragma unroll
        for (int mf = 0; mf < 2; ++mf) {
            const int ar = mf * 16 + fr;
            a0[mf] = *reinterpret_cast<const bf16x8*>(&sAc[(ar << 6) + ua0]);
            a1[mf] = *reinterpret_cast<const bf16x8*>(&sAc[(ar << 6) + ua1]);
        }

        // 2) B(i+1) reg loads (4 x dwordx4, coalesced, L2-resident)
        if (i < NITER - 1) {
            const char* bb = wqw + (size_t)(i + 1) * 32768;
            #pragma unroll
            for (int f = 0; f < 4; ++f)
                br[(i + 1) & 1][f] = *reinterpret_cast<const bf16x8*>(bb + f * 1024);
        }
        SCHEDB;

        // 3) drain B(i) (issued 1 iter ago), keep A(i+1)+B(i+1); MFMA K-half 0
        if (i == NITER - 1) { WAITV0; } else { WAITV8; }
        __builtin_amdgcn_s_setprio(1);
        #pragma unroll
        for (int mf = 0; mf < 2; ++mf)
            #pragma unroll
            for (int nf = 0; nf < 2; ++nf)
                acc[mf][nf] = __builtin_amdgcn_mfma_f32_16x16x32_bf16(a0[mf], br[i & 1][nf], acc[mf][nf], 0, 0, 0);
        __builtin_amdgcn_s_setprio(0);
        SCHEDB;

        // 4) combine A(i+1): drain A gathers (1 iter old), keep B(i+1); write sA
        if (i < NITER - 1) {
            WAITV4;
            unsigned short* sAn = const_cast<unsigned short*>(sA[(i + 1) & 1]);
            union { ushort4 u; __bf16 h[4]; } pk;
            #pragma unroll
            for (int j = 0; j < 4; ++j) {
                const unsigned u0 = (j & 2) ? ga0.y : ga0.x, u1 = (j & 2) ? ga1.y : ga1.x;
                const unsigned u2 = (j & 2) ? ga2.y : ga2.x, u3 = (j & 2) ? ga3.y : ga3.x;
                pk.h[j] = (__bf16)(wt_k.x * c2f(u0, j & 1) + wt_k.y * c2f(u1, j & 1)
                                 + wt_k.z * c2f(u2, j & 1) + wt_k.w * c2f(u3, j & 1));
            }
            *reinterpret_cast<ushort4*>(&sAn[aw_off]) = pk.u;
        }
        SCHEDB;

        // 5) issue A(i+2) gathers; tap meta reload when (i+2)%4 == 0
        if (i < NITER - 2) {
            const int ia = i + 2;
            if ((ia & 3) == 0) {
                const int kk = ia >> 2;
                wt_k = s_w[(kk << 5) + p];
                const int4 sa = s_a[(kk << 5) + p];
                aK0 = base_lane + ((size_t)sa.x << 9);
                aK1 = base_lane + ((size_t)sa.y << 9);
                aK2 = base_lane + ((size_t)sa.z << 9);
                aK3 = base_lane + ((size_t)sa.w << 9);
            }
            const int cb = (ia & 3) << 7;    // channel-block byte offset within the tap
            ga0 = *reinterpret_cast<const uint2*>(aK0 + cb);
            ga1 = *reinterpret_cast<const uint2*>(aK1 + cb);
            ga2 = *reinterpret_cast<const uint2*>(aK2 + cb);
            ga3 = *reinterpret_cast<const uint2*>(aK3 + cb);
        }
        SCHEDB;

        // 6) MFMA K-half 1 (B(i) half1 already in regs)
        __builtin_amdgcn_s_setprio(1);
        #pragma unroll
        for (int mf = 0; mf < 2; ++mf)
            #pragma unroll
            for (int nf = 0; nf < 2; ++nf)
                acc[mf][nf] = __builtin_amdgcn_mfma_f32_16x16x32_bf16(a1[mf], br[i & 1][2 + nf], acc[mf][nf], 0, 0, 0);
        __builtin_amdgcn_s_setprio(0);

        // 7) pre-barrier: drain only ds ops; B(i+1)x4 and A(i+2)x4 cross the barrier
        WAITLGKM0;
        __builtin_amdgcn_s_barrier();
        SCHEDB;
    }

    // ---- epilogue: rows m = mf*16 + fq*4 + j, cols n = wv*32 + nf*16 + fr ----
    float* ob = out + (size_t)b * (256 * 4096) + (ho << 6) + wo0;
    #pragma unroll
    for (int nf = 0; nf < 2; ++nf) {
        const int n = (wv << 5) + nf * 16 + fr;
        #pragma unroll
        for (int mf = 0; mf < 2; ++mf) {
            const int m = mf * 16 + (fq << 2);
            *reinterpret_cast<f32x4*>(&ob[(size_t)n * 4096 + m]) = acc[mf][nf];
        }
    }
}

// ---- fallback (ws too small): convert-on-the-fly weights, NCHW gathers ----
__global__ __launch_bounds__(256, 2)
void deform_gemm_fb(const float* __restrict__ x, const float* __restrict__ off,
                    const float* __restrict__ wf, float* __restrict__ out) {
    __shared__ float4 s_w[32 * 9];
    __shared__ int4   s_a[32 * 9];
    __shared__ unsigned short sA[2][32 * 32];
    __shared__ unsigned short sB[2][256 * 32];

    const int tid  = threadIdx.x;
    const int lane = tid & 63;
    const int wv   = tid >> 6;
    const int fr   = lane & 15;
    const int fq   = lane >> 4;
    const int bs  = ((blockIdx.x & 7) << 6) | (blockIdx.x >> 3);
    const int b   = bs >> 7;
    const int ho  = (bs >> 1) & 63;
    const int wo0 = (bs & 1) << 5;

    for (int i = tid; i < 32 * 9; i += 256) {
        const int k = i >> 5, p = i & 31, wo = wo0 + p;
        const int kh = k / 3, kw = k - kh * 3;
        const float dy = off[(((b * 18) + 2 * k    ) * 64 + ho) * 64 + wo];
        const float dx = off[(((b * 18) + 2 * k + 1) * 64 + ho) * 64 + wo];
        const float sy = (float)(ho - 1 + kh) + dy;
        const float sx = (float)(wo - 1 + kw) + dx;
        const float y0f = floorf(sy), x0f = floorf(sx);
        const float fy = sy - y0f, fx = sx - x0f;
        const int y0 = (int)y0f, x0 = (int)x0f;
        const int y1 = y0 + 1, x1 = x0 + 1;
        const bool vy0 = (unsigned)y0 < 64u, vy1 = (unsigned)y1 < 64u;
        const bool vx0 = (unsigned)x0 < 64u, vx1 = (unsigned)x1 < 64u;
        const int y0c = min(max(y0, 0), 63), y1c = min(max(y1, 0), 63);
        const int x0c = min(max(x0, 0), 63), x1c = min(max(x1, 0), 63);
        float4 wt;
        wt.x = (1.f - fy) * (1.f - fx) * ((vy0 & vx0) ? 1.f : 0.f);
        wt.y = (1.f - fy) * fx         * ((vy0 & vx1) ? 1.f : 0.f);
        wt.z = fy * (1.f - fx)         * ((vy1 & vx0) ? 1.f : 0.f);
        wt.w = fy * fx                 * ((vy1 & vx1) ? 1.f : 0.f);
        s_w[i] = wt;
        s_a[i] = make_int4((y0c << 6) + x0c, (y0c << 6) + x1c,
                           (y1c << 6) + x0c, (y1c << 6) + x1c);
    }

    f32x4 acc[2][4];
    #pragma unroll
    for (int mf = 0; mf < 2; ++mf)
        #pragma unroll
        for (int nf = 0; nf < 4; ++nf)
            acc[mf][nf] = (f32x4){0.f, 0.f, 0.f, 0.f};

    const float* xb = x + (size_t)b * (256 * 4096);
    const int p  = tid & 31;
    const int rq = tid >> 5;
    const int aw_off = (p << 5) + ((((rq >> 1) ^ ((p >> 1) & 3)) << 3)) + ((rq & 1) << 2);

    int brow[4], bcol[4];
    #pragma unroll
    for (int q = 0; q < 4; ++q) {
        brow[q] = (wv << 6) + (q << 4) + (lane >> 2);
        bcol[q] = ((lane & 3) ^ ((brow[q] >> 1) & 3)) << 3;
    }
    const int bphys = (lane & 3) << 3;

    __syncthreads();

    for (int t = 0; t < 72; ++t) {
        const int cur = t & 1;
        const int r0 = t * 32;
        union { ushort4 u; __bf16 h[4]; } pk;
        #pragma unroll
        for (int j = 0; j < 4; ++j) {
            const int r = r0 + rq * 4 + j;
            const int c = r / 9, k = r - c * 9;
            const float4 wt = s_w[(k << 5) + p];
            const int4 ad = s_a[(k << 5) + p];
            const float* xp = xb + (c << 12);
            pk.h[j] = (__bf16)(wt.x * xp[ad.x] + wt.y * xp[ad.y]
                             + wt.z * xp[ad.z] + wt.w * xp[ad.w]);
        }
        *reinterpret_cast<ushort4*>(&sA[cur][aw_off]) = pk.u;
        #pragma unroll
        for (int q = 0; q < 4; ++q) {
            const float4* s = reinterpret_cast<const float4*>(wf + (size_t)brow[q] * RTOT + r0 + bcol[q]);
            float4 f0 = s[0], f1 = s[1];
            union { uint4 u; __bf16 h[8]; } ub;
            ub.h[0]=(__bf16)f0.x; ub.h[1]=(__bf16)f0.y; ub.h[2]=(__bf16)f0.z; ub.h[3]=(__bf16)f0.w;
            ub.h[4]=(__bf16)f1.x; ub.h[5]=(__bf16)f1.y; ub.h[6]=(__bf16)f1.z; ub.h[7]=(__bf16)f1.w;
            *reinterpret_cast<uint4*>(&sB[cur][(brow[q] << 5) + bphys]) = ub.u;
        }
        __syncthreads();
        bf16x8 af[2], bfr[4];
        #pragma unroll
        for (int mf = 0; mf < 2; ++mf) {
            const int row = mf * 16 + fr;
            af[mf] = *reinterpret_cast<const bf16x8*>(&sA[cur][(row << 5) + ((fq ^ ((row >> 1) & 3)) << 3)]);
        }
        #pragma unroll
        for (int nf = 0; nf < 4; ++nf) {
            const int row = (wv << 6) + nf * 16 + fr;
            bfr[nf] = *reinterpret_cast<const bf16x8*>(&sB[cur][(row << 5) + ((fq ^ ((row >> 1) & 3)) << 3)]);
        }
        #pragma unroll
        for (int mf = 0; mf < 2; ++mf)
            #pragma unroll
            for (int nf = 0; nf < 4; ++nf)
                acc[mf][nf] = __builtin_amdgcn_mfma_f32_16x16x32_bf16(af[mf], bfr[nf], acc[mf][nf], 0, 0, 0);
        __syncthreads();
    }

    float* ob = out + (size_t)b * (256 * 4096) + (ho << 6) + wo0;
    #pragma unroll
    for (int nf = 0; nf < 4; ++nf) {
        const int n = (wv << 6) + nf * 16 + fr;
        #pragma unroll
        for (int mf = 0; mf < 2; ++mf) {
            const int m = mf * 16 + (fq << 2);
            *reinterpret_cast<f32x4*>(&ob[(size_t)n * 4096 + m]) = acc[mf][nf];
        }
    }
}

extern "C" void kernel_launch(void* const* d_in, const int* in_sizes, int n_in,
                              void* d_out, int out_size, void* d_ws, size_t ws_size,
                              hipStream_t stream) {
    const float* x   = (const float*)d_in[0];
    const float* off = (const float*)d_in[1];
    const float* w   = (const float*)d_in[2];
    float* out = (float*)d_out;

    const size_t xh_bytes = (size_t)4 * 64 * 64 * 256 * sizeof(__bf16);   // 8.4 MB
    const size_t wq_bytes = (size_t)NITER * 8 * 4 * 64 * 16;              // 1.18 MB
    if (ws_size >= xh_bytes + wq_bytes) {
        __bf16* xh = (__bf16*)d_ws;
        __bf16* wq = (__bf16*)((char*)d_ws + xh_bytes);
        nchw_to_nhwc_bf16<<<dim3(256), dim3(256), 0, stream>>>(x, xh);
        weight_prep_frag<<<dim3(288), dim3(256), 0, stream>>>(w, wq);
        deform_gemm_nhwc<<<dim3(512), dim3(512), 0, stream>>>(off, xh, wq, out);
    } else {
        deform_gemm_fb<<<dim3(512), dim3(256), 0, stream>>>(x, off, w, out);
    }
}

// Round 15
// 51.885 us; speedup vs baseline: 1.1671x; 1.1671x over previous
//
#include <hip/hip_runtime.h>
#include <hip/hip_bf16.h>
#include <cstdint>

typedef __bf16 bf16x8 __attribute__((ext_vector_type(8)));
typedef float  f32x4  __attribute__((ext_vector_type(4)));
typedef unsigned short ushort8v __attribute__((ext_vector_type(8)));

constexpr int RTOT  = 2304;          // 9 taps * 256 channels, r = k*256 + c
constexpr int NIT   = 18;            // BK = 128 per iteration

#define WAITV16   asm volatile("s_waitcnt vmcnt(16)" ::: "memory")
#define WAITV8    asm volatile("s_waitcnt vmcnt(8)" ::: "memory")
#define WAITV0    asm volatile("s_waitcnt vmcnt(0)" ::: "memory")
#define WAITLGKM0 asm volatile("s_waitcnt lgkmcnt(0)" ::: "memory")
#define SCHEDB    __builtin_amdgcn_sched_barrier(0)

__device__ __forceinline__ float c2f(unsigned w, int hi) {
    union { unsigned u; float f; } v;
    v.u = hi ? (w & 0xffff0000u) : (w << 16);
    return v.f;
}

// ---- prep 1: x [4,256,64,64] f32 (NCHW) -> xh [4,64,64,256] bf16 (NHWC) ----
__global__ __launch_bounds__(256)
void nchw_to_nhwc_bf16(const float* __restrict__ x, __bf16* __restrict__ xh) {
    __shared__ unsigned short tile[256][70];
    const int tid = threadIdx.x;
    const int b = blockIdx.x >> 6;
    const int y = blockIdx.x & 63;
    const float* xp = x + (size_t)b * (256 * 4096) + y * 64;
    #pragma unroll 4
    for (int it = 0; it < 64; ++it) {
        const int ci = it * 4 + (tid >> 6);
        const int xi = tid & 63;
        __bf16 h = (__bf16)xp[(size_t)ci * 4096 + xi];
        tile[ci][xi] = *reinterpret_cast<unsigned short*>(&h);
    }
    __syncthreads();
    unsigned short* op = reinterpret_cast<unsigned short*>(xh) + ((size_t)b * 64 + y) * 64 * 256;
    #pragma unroll 4
    for (int it = 0; it < 64; ++it)
        op[(size_t)it * 256 + tid] = tile[tid][it];
}

// ---- prep 2: w [co][c][k] f32 -> wq, pre-permuted per-lane MFMA B fragments ----
// Fragment (i8, wv, f), f = half*2 + nf: lane l holds 8 weights
//   co = wv*32 + nf*16 + (l&15), r = i8*64 + half*32 + (l>>4)*8 + j  (r = k*256+c).
// Byte address: (i8*8 + wv)*4096 + f*1024 + l*16.
__global__ __launch_bounds__(256)
void weight_prep_frag(const float* __restrict__ w, __bf16* __restrict__ wq) {
    const int e = blockIdx.x * 256 + threadIdx.x;   // 73728 fragment-lanes
    const int l  = e & 63;
    const int f  = (e >> 6) & 3;
    const int wv = (e >> 8) & 7;
    const int i8 = e >> 11;
    const int nf = f & 1, half = f >> 1;
    const int co = wv * 32 + nf * 16 + (l & 15);
    const int rb = i8 * 64 + half * 32 + ((l >> 4) << 3);
    union { ushort4 u2[2]; __bf16 h[8]; } pk;
    #pragma unroll
    for (int j = 0; j < 8; ++j) {
        const int r = rb + j;
        const int c = r & 255, k = r >> 8;
        pk.h[j] = (__bf16)w[co * 2304 + c * 9 + k];
    }
    unsigned short* dst = reinterpret_cast<unsigned short*>(wq) + (size_t)e * 8;
    *reinterpret_cast<ushort4*>(dst)     = pk.u2[0];
    *reinterpret_cast<ushort4*>(dst + 4) = pk.u2[1];
}

// ---- main: fused deformable implicit GEMM, BK=128, A-only LDS, B L2->reg ----
// Block = 64 wo x 256 co, 512 threads / 8 waves (1M x 8N); wave slab 64(M) x 32(N).
// Grid = 256 -> 1 block/CU. Iter i covers r = i*128..+127: tap k = i>>1,
// channel block (i&1)*128. Per iter per wave: 16 ds_read_b128 (A, 4 quarters) +
// 8 B reg-loads (unique per wave) + 8 A-gathers + 32 MFMA + ONE barrier.
// Halves barrier count + per-iter fixed latency vs BK=64 (round-13).
// Wait ladder (FIFO: B(i+1)x8 @s2, A(i+2)x8 @s5): WAITV16 pre-MFMA drains B(i)
// (1 iter old); WAITV8 at combine drains A(i+1) (1 iter old), keeps B(i+1);
// pre-barrier lgkmcnt(0) only -- B(i+1)+A(i+2) (16 loads) cross the barrier.
// A LDS rows = 128 ch = 16 x 16B units, XOR-swizzled by (row&15); frag rows have
// ar&15 == fr so write/read swizzles match.
__global__ __launch_bounds__(512, 1)
void deform_gemm_nhwc(const float* __restrict__ off, const __bf16* __restrict__ xh,
                      const __bf16* __restrict__ wq, float* __restrict__ out) {
    __shared__ float4 s_w[64 * 9];
    __shared__ int4   s_a[64 * 9];
    __shared__ unsigned short sA[2][64 * 128];   // [buf][p*128 + ch], XOR-swizzled

    const int tid  = threadIdx.x;
    const int lane = tid & 63;
    const int wv   = tid >> 6;               // 0..7 = N-eighth
    const int fr   = lane & 15;
    const int fq   = lane >> 4;

    const int bs = ((blockIdx.x & 7) << 5) | (blockIdx.x >> 3);  // bijective XCD swizzle
    const int b  = bs >> 6;
    const int ho = bs & 63;

    // ---- per-(k, p) bilinear metadata (9 taps x 64 positions) ----
    for (int i = tid; i < 576; i += 512) {
        const int k = i >> 6, p = i & 63;
        const int kh = k / 3, kw = k - kh * 3;
        const float dy = off[(((b * 18) + 2 * k    ) * 64 + ho) * 64 + p];
        const float dx = off[(((b * 18) + 2 * k + 1) * 64 + ho) * 64 + p];
        const float sy = (float)(ho - 1 + kh) + dy;
        const float sx = (float)(p  - 1 + kw) + dx;
        const float y0f = floorf(sy), x0f = floorf(sx);
        const float fy = sy - y0f, fx = sx - x0f;
        const int y0 = (int)y0f, x0 = (int)x0f;
        const int y1 = y0 + 1, x1 = x0 + 1;
        const bool vy0 = (unsigned)y0 < 64u, vy1 = (unsigned)y1 < 64u;
        const bool vx0 = (unsigned)x0 < 64u, vx1 = (unsigned)x1 < 64u;
        const int y0c = min(max(y0, 0), 63), y1c = min(max(y1, 0), 63);
        const int x0c = min(max(x0, 0), 63), x1c = min(max(x1, 0), 63);
        float4 wt;
        wt.x = (1.f - fy) * (1.f - fx) * ((vy0 & vx0) ? 1.f : 0.f);
        wt.y = (1.f - fy) * fx         * ((vy0 & vx1) ? 1.f : 0.f);
        wt.z = fy * (1.f - fx)         * ((vy1 & vx0) ? 1.f : 0.f);
        wt.w = fy * fx                 * ((vy1 & vx1) ? 1.f : 0.f);
        s_w[i] = wt;
        s_a[i] = make_int4((y0c << 6) + x0c, (y0c << 6) + x1c,
                           (y1c << 6) + x0c, (y1c << 6) + x1c);
    }

    f32x4 acc[4][2];
    #pragma unroll
    for (int mf = 0; mf < 4; ++mf)
        #pragma unroll
        for (int nf = 0; nf < 2; ++nf)
            acc[mf][nf] = (f32x4){0.f, 0.f, 0.f, 0.f};

    const __bf16* xb = xh + ((size_t)b << 20);
    // A-gen: 512 threads = 64 positions x 8 octets; per iter each thread covers
    // ch oct*8..+7 (set0) and 64+oct*8..+7 (set1) of the 128-ch block.
    const int p   = tid >> 3;                // 0..63
    const int oct = tid & 7;
    const int u0 = oct ^ (p & 15);           // set0 phys unit
    const int u1 = (8 + oct) ^ (p & 15);     // set1 phys unit
    const int aw0 = (p << 7) + (u0 << 3);    // ushort offsets
    const int aw1 = (p << 7) + (u1 << 3);
    const char* base_lane = (const char*)xb + (oct << 4);

    // B fragment source for this wave (unique per wv)
    const char* wqw = (const char*)wq + ((size_t)wv << 12) + (lane << 4);

    // A fragment read offsets (swizzled units) per K32 quarter q: unit (q*4+fq)^fr
    int ua[4];
    #pragma unroll
    for (int q = 0; q < 4; ++q)
        ua[q] = (((q << 2) + fq) ^ fr) << 3;

    __syncthreads();  // meta ready

    float4 wt_k;
    uint4 ga0, ga1, ga2, ga3, gb0, gb1, gb2, gb3;
    const char *aK0, *aK1, *aK2, *aK3;
    bf16x8 br[2][8];                         // B reg double buffer (static idx under unroll)

    {   // tap 0 meta
        wt_k = s_w[p];
        const int4 sa = s_a[p];
        aK0 = base_lane + ((size_t)sa.x << 9);
        aK1 = base_lane + ((size_t)sa.y << 9);
        aK2 = base_lane + ((size_t)sa.z << 9);
        aK3 = base_lane + ((size_t)sa.w << 9);
    }

    // ---- prologue: load B(0) x8; gather+combine A(0); issue A(1) ----
    {
        #pragma unroll
        for (int f = 0; f < 4; ++f) {
            br[0][f]     = *reinterpret_cast<const bf16x8*>(wqw + f * 1024);
            br[0][4 + f] = *reinterpret_cast<const bf16x8*>(wqw + 32768 + f * 1024);
        }
        ga0 = *reinterpret_cast<const uint4*>(aK0);
        ga1 = *reinterpret_cast<const uint4*>(aK1);
        ga2 = *reinterpret_cast<const uint4*>(aK2);
        ga3 = *reinterpret_cast<const uint4*>(aK3);
        gb0 = *reinterpret_cast<const uint4*>(aK0 + 128);
        gb1 = *reinterpret_cast<const uint4*>(aK1 + 128);
        gb2 = *reinterpret_cast<const uint4*>(aK2 + 128);
        gb3 = *reinterpret_cast<const uint4*>(aK3 + 128);
        WAITV0;
        {
            const unsigned* w0 = reinterpret_cast<const unsigned*>(&ga0);
            const unsigned* w1 = reinterpret_cast<const unsigned*>(&ga1);
            const unsigned* w2 = reinterpret_cast<const unsigned*>(&ga2);
            const unsigned* w3 = reinterpret_cast<const unsigned*>(&ga3);
            union { ushort8v u; __bf16 h[8]; } pk;
            #pragma unroll
            for (int j = 0; j < 8; ++j)
                pk.h[j] = (__bf16)(wt_k.x * c2f(w0[j >> 1], j & 1) + wt_k.y * c2f(w1[j >> 1], j & 1)
                                 + wt_k.z * c2f(w2[j >> 1], j & 1) + wt_k.w * c2f(w3[j >> 1], j & 1));
            *reinterpret_cast<ushort8v*>(&sA[0][aw0]) = pk.u;
            const unsigned* v0 = reinterpret_cast<const unsigned*>(&gb0);
            const unsigned* v1 = reinterpret_cast<const unsigned*>(&gb1);
            const unsigned* v2 = reinterpret_cast<const unsigned*>(&gb2);
            const unsigned* v3 = reinterpret_cast<const unsigned*>(&gb3);
            #pragma unroll
            for (int j = 0; j < 8; ++j)
                pk.h[j] = (__bf16)(wt_k.x * c2f(v0[j >> 1], j & 1) + wt_k.y * c2f(v1[j >> 1], j & 1)
                                 + wt_k.z * c2f(v2[j >> 1], j & 1) + wt_k.w * c2f(v3[j >> 1], j & 1));
            *reinterpret_cast<ushort8v*>(&sA[0][aw1]) = pk.u;
        }
        // issue A(1): same tap, channel block 1 (byte offsets 256 / 384)
        ga0 = *reinterpret_cast<const uint4*>(aK0 + 256);
        ga1 = *reinterpret_cast<const uint4*>(aK1 + 256);
        ga2 = *reinterpret_cast<const uint4*>(aK2 + 256);
        ga3 = *reinterpret_cast<const uint4*>(aK3 + 256);
        gb0 = *reinterpret_cast<const uint4*>(aK0 + 384);
        gb1 = *reinterpret_cast<const uint4*>(aK1 + 384);
        gb2 = *reinterpret_cast<const uint4*>(aK2 + 384);
        gb3 = *reinterpret_cast<const uint4*>(aK3 + 384);
        SCHEDB;
        WAITLGKM0;
        __builtin_amdgcn_s_barrier();
        SCHEDB;
    }

    // ---- main loop: 18 iterations of BK=128 ----
    #pragma unroll 2
    for (int i = 0; i < NIT; ++i) {
        const unsigned short* sAc = sA[i & 1];

        // 1) A fragment reads for quarters 0,1 (8 x ds_read_b128)
        bf16x8 aQ0[4], aQ1[4];
        #pragma unroll
        for (int mf = 0; mf < 4; ++mf) {
            const int ar = mf * 16 + fr;
            aQ0[mf] = *reinterpret_cast<const bf16x8*>(&sAc[(ar << 7) + ua[0]]);
            aQ1[mf] = *reinterpret_cast<const bf16x8*>(&sAc[(ar << 7) + ua[1]]);
        }

        // 2) B(i+1) reg loads (8 x dwordx4, coalesced, L2-resident, unique per wave)
        if (i < NIT - 1) {
            const char* bb = wqw + (size_t)(2 * (i + 1)) * 32768;
            #pragma unroll
            for (int f = 0; f < 4; ++f) {
                br[(i + 1) & 1][f]     = *reinterpret_cast<const bf16x8*>(bb + f * 1024);
                br[(i + 1) & 1][4 + f] = *reinterpret_cast<const bf16x8*>(bb + 32768 + f * 1024);
            }
        }
        SCHEDB;

        // 3) drain B(i) (1 iter old), keep A(i+1)x8 + B(i+1)x8; MFMA quarters 0,1
        if (i == NIT - 1) { WAITV0; } else { WAITV16; }
        __builtin_amdgcn_s_setprio(1);
        #pragma unroll
        for (int mf = 0; mf < 4; ++mf)
            #pragma unroll
            for (int nf = 0; nf < 2; ++nf)
                acc[mf][nf] = __builtin_amdgcn_mfma_f32_16x16x32_bf16(aQ0[mf], br[i & 1][nf], acc[mf][nf], 0, 0, 0);
        #pragma unroll
        for (int mf = 0; mf < 4; ++mf)
            #pragma unroll
            for (int nf = 0; nf < 2; ++nf)
                acc[mf][nf] = __builtin_amdgcn_mfma_f32_16x16x32_bf16(aQ1[mf], br[i & 1][2 + nf], acc[mf][nf], 0, 0, 0);
        __builtin_amdgcn_s_setprio(0);
        SCHEDB;

        // 3.5) A fragment reads for quarters 2,3 (latency hides under combine)
        bf16x8 aQ2[4], aQ3[4];
        #pragma unroll
        for (int mf = 0; mf < 4; ++mf) {
            const int ar = mf * 16 + fr;
            aQ2[mf] = *reinterpret_cast<const bf16x8*>(&sAc[(ar << 7) + ua[2]]);
            aQ3[mf] = *reinterpret_cast<const bf16x8*>(&sAc[(ar << 7) + ua[3]]);
        }

        // 4) combine A(i+1): drain gathers (1 iter old), keep B(i+1); write other buf
        if (i < NIT - 1) {
            WAITV8;
            unsigned short* sAn = const_cast<unsigned short*>(sA[(i + 1) & 1]);
            const unsigned* w0 = reinterpret_cast<const unsigned*>(&ga0);
            const unsigned* w1 = reinterpret_cast<const unsigned*>(&ga1);
            const unsigned* w2 = reinterpret_cast<const unsigned*>(&ga2);
            const unsigned* w3 = reinterpret_cast<const unsigned*>(&ga3);
            union { ushort8v u; __bf16 h[8]; } pk;
            #pragma unroll
            for (int j = 0; j < 8; ++j)
                pk.h[j] = (__bf16)(wt_k.x * c2f(w0[j >> 1], j & 1) + wt_k.y * c2f(w1[j >> 1], j & 1)
                                 + wt_k.z * c2f(w2[j >> 1], j & 1) + wt_k.w * c2f(w3[j >> 1], j & 1));
            *reinterpret_cast<ushort8v*>(&sAn[aw0]) = pk.u;
            const unsigned* v0 = reinterpret_cast<const unsigned*>(&gb0);
            const unsigned* v1 = reinterpret_cast<const unsigned*>(&gb1);
            const unsigned* v2 = reinterpret_cast<const unsigned*>(&gb2);
            const unsigned* v3 = reinterpret_cast<const unsigned*>(&gb3);
            #pragma unroll
            for (int j = 0; j < 8; ++j)
                pk.h[j] = (__bf16)(wt_k.x * c2f(v0[j >> 1], j & 1) + wt_k.y * c2f(v1[j >> 1], j & 1)
                                 + wt_k.z * c2f(v2[j >> 1], j & 1) + wt_k.w * c2f(v3[j >> 1], j & 1));
            *reinterpret_cast<ushort8v*>(&sAn[aw1]) = pk.u;
        }
        SCHEDB;

        // 5) issue A(i+2) gathers; tap meta reload when (i+2) even
        if (i < NIT - 2) {
            const int ia = i + 2;
            if ((ia & 1) == 0) {
                const int kk = ia >> 1;
                wt_k = s_w[(kk << 6) + p];
                const int4 sa = s_a[(kk << 6) + p];
                aK0 = base_lane + ((size_t)sa.x << 9);
                aK1 = base_lane + ((size_t)sa.y << 9);
                aK2 = base_lane + ((size_t)sa.z << 9);
                aK3 = base_lane + ((size_t)sa.w << 9);
            }
            const int cb = (ia & 1) << 8;    // 0 or 256 bytes
            ga0 = *reinterpret_cast<const uint4*>(aK0 + cb);
            ga1 = *reinterpret_cast<const uint4*>(aK1 + cb);
            ga2 = *reinterpret_cast<const uint4*>(aK2 + cb);
            ga3 = *reinterpret_cast<const uint4*>(aK3 + cb);
            gb0 = *reinterpret_cast<const uint4*>(aK0 + cb + 128);
            gb1 = *reinterpret_cast<const uint4*>(aK1 + cb + 128);
            gb2 = *reinterpret_cast<const uint4*>(aK2 + cb + 128);
            gb3 = *reinterpret_cast<const uint4*>(aK3 + cb + 128);
        }
        SCHEDB;

        // 6) MFMA quarters 2,3
        __builtin_amdgcn_s_setprio(1);
        #pragma unroll
        for (int mf = 0; mf < 4; ++mf)
            #pragma unroll
            for (int nf = 0; nf < 2; ++nf)
                acc[mf][nf] = __builtin_amdgcn_mfma_f32_16x16x32_bf16(aQ2[mf], br[i & 1][4 + nf], acc[mf][nf], 0, 0, 0);
        #pragma unroll
        for (int mf = 0; mf < 4; ++mf)
            #pragma unroll
            for (int nf = 0; nf < 2; ++nf)
                acc[mf][nf] = __builtin_amdgcn_mfma_f32_16x16x32_bf16(aQ3[mf], br[i & 1][6 + nf], acc[mf][nf], 0, 0, 0);
        __builtin_amdgcn_s_setprio(0);

        // 7) pre-barrier: drain only ds ops; B(i+1)x8 + A(i+2)x8 cross the barrier
        WAITLGKM0;
        __builtin_amdgcn_s_barrier();
        SCHEDB;
    }

    // ---- epilogue: rows m = mf*16 + fq*4 + j, cols n = wv*32 + nf*16 + fr ----
    float* ob = out + (size_t)b * (256 * 4096) + (ho << 6);
    #pragma unroll
    for (int nf = 0; nf < 2; ++nf) {
        const int n = (wv << 5) + nf * 16 + fr;
        #pragma unroll
        for (int mf = 0; mf < 4; ++mf) {
            const int m = mf * 16 + (fq << 2);
            *reinterpret_cast<f32x4*>(&ob[(size_t)n * 4096 + m]) = acc[mf][nf];
        }
    }
}

// ---- fallback (ws too small): convert-on-the-fly weights, NCHW gathers ----
__global__ __launch_bounds__(256, 2)
void deform_gemm_fb(const float* __restrict__ x, const float* __restrict__ off,
                    const float* __restrict__ wf, float* __restrict__ out) {
    __shared__ float4 s_w[32 * 9];
    __shared__ int4   s_a[32 * 9];
    __shared__ unsigned short sA[2][32 * 32];
    __shared__ unsigned short sB[2][256 * 32];

    const int tid  = threadIdx.x;
    const int lane = tid & 63;
    const int wv   = tid >> 6;
    const int fr   = lane & 15;
    const int fq   = lane >> 4;
    const int bs  = ((blockIdx.x & 7) << 6) | (blockIdx.x >> 3);
    const int b   = bs >> 7;
    const int ho  = (bs >> 1) & 63;
    const int wo0 = (bs & 1) << 5;

    for (int i = tid; i < 32 * 9; i += 256) {
        const int k = i >> 5, p = i & 31, wo = wo0 + p;
        const int kh = k / 3, kw = k - kh * 3;
        const float dy = off[(((b * 18) + 2 * k    ) * 64 + ho) * 64 + wo];
        const float dx = off[(((b * 18) + 2 * k + 1) * 64 + ho) * 64 + wo];
        const float sy = (float)(ho - 1 + kh) + dy;
        const float sx = (float)(wo - 1 + kw) + dx;
        const float y0f = floorf(sy), x0f = floorf(sx);
        const float fy = sy - y0f, fx = sx - x0f;
        const int y0 = (int)y0f, x0 = (int)x0f;
        const int y1 = y0 + 1, x1 = x0 + 1;
        const bool vy0 = (unsigned)y0 < 64u, vy1 = (unsigned)y1 < 64u;
        const bool vx0 = (unsigned)x0 < 64u, vx1 = (unsigned)x1 < 64u;
        const int y0c = min(max(y0, 0), 63), y1c = min(max(y1, 0), 63);
        const int x0c = min(max(x0, 0), 63), x1c = min(max(x1, 0), 63);
        float4 wt;
        wt.x = (1.f - fy) * (1.f - fx) * ((vy0 & vx0) ? 1.f : 0.f);
        wt.y = (1.f - fy) * fx         * ((vy0 & vx1) ? 1.f : 0.f);
        wt.z = fy * (1.f - fx)         * ((vy1 & vx0) ? 1.f : 0.f);
        wt.w = fy * fx                 * ((vy1 & vx1) ? 1.f : 0.f);
        s_w[i] = wt;
        s_a[i] = make_int4((y0c << 6) + x0c, (y0c << 6) + x1c,
                           (y1c << 6) + x0c, (y1c << 6) + x1c);
    }

    f32x4 acc[2][4];
    #pragma unroll
    for (int mf = 0; mf < 2; ++mf)
        #pragma unroll
        for (int nf = 0; nf < 4; ++nf)
            acc[mf][nf] = (f32x4){0.f, 0.f, 0.f, 0.f};

    const float* xb = x + (size_t)b * (256 * 4096);
    const int p  = tid & 31;
    const int rq = tid >> 5;
    const int aw_off = (p << 5) + ((((rq >> 1) ^ ((p >> 1) & 3)) << 3)) + ((rq & 1) << 2);

    int brow[4], bcol[4];
    #pragma unroll
    for (int q = 0; q < 4; ++q) {
        brow[q] = (wv << 6) + (q << 4) + (lane >> 2);
        bcol[q] = ((lane & 3) ^ ((brow[q] >> 1) & 3)) << 3;
    }
    const int bphys = (lane & 3) << 3;

    __syncthreads();

    for (int t = 0; t < 72; ++t) {
        const int cur = t & 1;
        const int r0 = t * 32;
        union { ushort4 u; __bf16 h[4]; } pk;
        #pragma unroll
        for (int j = 0; j < 4; ++j) {
            const int r = r0 + rq * 4 + j;
            const int c = r / 9, k = r - c * 9;
            const float4 wt = s_w[(k << 5) + p];
            const int4 ad = s_a[(k << 5) + p];
            const float* xp = xb + (c << 12);
            pk.h[j] = (__bf16)(wt.x * xp[ad.x] + wt.y * xp[ad.y]
                             + wt.z * xp[ad.z] + wt.w * xp[ad.w]);
        }
        *reinterpret_cast<ushort4*>(&sA[cur][aw_off]) = pk.u;
        #pragma unroll
        for (int q = 0; q < 4; ++q) {
            const float4* s = reinterpret_cast<const float4*>(wf + (size_t)brow[q] * RTOT + r0 + bcol[q]);
            float4 f0 = s[0], f1 = s[1];
            union { uint4 u; __bf16 h[8]; } ub;
            ub.h[0]=(__bf16)f0.x; ub.h[1]=(__bf16)f0.y; ub.h[2]=(__bf16)f0.z; ub.h[3]=(__bf16)f0.w;
            ub.h[4]=(__bf16)f1.x; ub.h[5]=(__bf16)f1.y; ub.h[6]=(__bf16)f1.z; ub.h[7]=(__bf16)f1.w;
            *reinterpret_cast<uint4*>(&sB[cur][(brow[q] << 5) + bphys]) = ub.u;
        }
        __syncthreads();
        bf16x8 af[2], bfr[4];
        #pragma unroll
        for (int mf = 0; mf < 2; ++mf) {
            const int row = mf * 16 + fr;
            af[mf] = *reinterpret_cast<const bf16x8*>(&sA[cur][(row << 5) + ((fq ^ ((row >> 1) & 3)) << 3)]);
        }
        #pragma unroll
        for (int nf = 0; nf < 4; ++nf) {
            const int row = (wv << 6) + nf * 16 + fr;
            bfr[nf] = *reinterpret_cast<const bf16x8*>(&sB[cur][(row << 5) + ((fq ^ ((row >> 1) & 3)) << 3)]);
        }
        #pragma unroll
        for (int mf = 0; mf < 2; ++mf)
            #pragma unroll
            for (int nf = 0; nf < 4; ++nf)
                acc[mf][nf] = __builtin_amdgcn_mfma_f32_16x16x32_bf16(af[mf], bfr[nf], acc[mf][nf], 0, 0, 0);
        __syncthreads();
    }

    float* ob = out + (size_t)b * (256 * 4096) + (ho << 6) + wo0;
    #pragma unroll
    for (int nf = 0; nf < 4; ++nf) {
        const int n = (wv << 6) + nf * 16 + fr;
        #pragma unroll
        for (int mf = 0; mf < 2; ++mf) {
            const int m = mf * 16 + (fq << 2);
            *reinterpret_cast<f32x4*>(&ob[(size_t)n * 4096 + m]) = acc[mf][nf];
        }
    }
}

extern "C" void kernel_launch(void* const* d_in, const int* in_sizes, int n_in,
                              void* d_out, int out_size, void* d_ws, size_t ws_size,
                              hipStream_t stream) {
    const float* x   = (const float*)d_in[0];
    const float* off = (const float*)d_in[1];
    const float* w   = (const float*)d_in[2];
    float* out = (float*)d_out;

    const size_t xh_bytes = (size_t)4 * 64 * 64 * 256 * sizeof(__bf16);   // 8.4 MB
    const size_t wq_bytes = (size_t)36 * 8 * 4 * 64 * 16;                 // 1.18 MB
    if (ws_size >= xh_bytes + wq_bytes) {
        __bf16* xh = (__bf16*)d_ws;
        __bf16* wq = (__bf16*)((char*)d_ws + xh_bytes);
        nchw_to_nhwc_bf16<<<dim3(256), dim3(256), 0, stream>>>(x, xh);
        weight_prep_frag<<<dim3(288), dim3(256), 0, stream>>>(w, wq);
        deform_gemm_nhwc<<<dim3(256), dim3(512), 0, stream>>>(off, xh, wq, out);
    } else {
        deform_gemm_fb<<<dim3(512), dim3(256), 0, stream>>>(x, off, w, out);
    }
}

// Round 16
// 47.516 us; speedup vs baseline: 1.2744x; 1.0920x over previous
//
#include <hip/hip_runtime.h>
#include <hip/hip_bf16.h>
#include <cstdint>

typedef __bf16 bf16x8 __attribute__((ext_vector_type(8)));
typedef float  f32x4  __attribute__((ext_vector_type(4)));
typedef unsigned short ushort8v __attribute__((ext_vector_type(8)));

constexpr int RTOT  = 2304;          // 9 taps * 256 channels, r = k*256 + c
constexpr int NITER = 36;            // BK = 64 per iteration

#define WAITV8    asm volatile("s_waitcnt vmcnt(8)" ::: "memory")
#define WAITV4    asm volatile("s_waitcnt vmcnt(4)" ::: "memory")
#define WAITV0    asm volatile("s_waitcnt vmcnt(0)" ::: "memory")
#define WAITLGKM0 asm volatile("s_waitcnt lgkmcnt(0)" ::: "memory")
#define SCHEDB    __builtin_amdgcn_sched_barrier(0)

__device__ __forceinline__ float c2f(unsigned w, int hi) {
    union { unsigned u; float f; } v;
    v.u = hi ? (w & 0xffff0000u) : (w << 16);
    return v.f;
}

// ---- merged prep: one launch does BOTH transforms ----
// Blocks [0, 256):   x [4,256,64,64] f32 (NCHW) -> xh [4,64,64,256] bf16 (NHWC)
// Blocks [256, 544): w [co][c][k] f32 -> wq, per-lane MFMA B fragments:
//   fragment (i8, wv, f), f = half*2+nf: lane l holds co = wv*32+nf*16+(l&15),
//   r = i8*64 + half*32 + (l>>4)*8 + j (r = k*256+c); addr (i8*8+wv)*4096+f*1024+l*16.
__global__ __launch_bounds__(256)
void prep_merged(const float* __restrict__ x, __bf16* __restrict__ xh,
                 const float* __restrict__ w, __bf16* __restrict__ wq) {
    __shared__ unsigned short tile[256][70];
    const int tid = threadIdx.x;
    if (blockIdx.x < 256) {
        const int b = blockIdx.x >> 6;
        const int y = blockIdx.x & 63;
        const float* xp = x + (size_t)b * (256 * 4096) + y * 64;
        #pragma unroll 4
        for (int it = 0; it < 64; ++it) {
            const int ci = it * 4 + (tid >> 6);
            const int xi = tid & 63;
            __bf16 h = (__bf16)xp[(size_t)ci * 4096 + xi];
            tile[ci][xi] = *reinterpret_cast<unsigned short*>(&h);
        }
        __syncthreads();
        unsigned short* op = reinterpret_cast<unsigned short*>(xh) + ((size_t)b * 64 + y) * 64 * 256;
        #pragma unroll 4
        for (int it = 0; it < 64; ++it)
            op[(size_t)it * 256 + tid] = tile[tid][it];
    } else {
        const int e = (blockIdx.x - 256) * 256 + tid;   // 73728 fragment-lanes
        const int l  = e & 63;
        const int f  = (e >> 6) & 3;
        const int wv = (e >> 8) & 7;
        const int i8 = e >> 11;
        const int nf = f & 1, half = f >> 1;
        const int co = wv * 32 + nf * 16 + (l & 15);
        const int rb = i8 * 64 + half * 32 + ((l >> 4) << 3);
        union { ushort4 u2[2]; __bf16 h[8]; } pk;
        #pragma unroll
        for (int j = 0; j < 8; ++j) {
            const int r = rb + j;
            const int c = r & 255, k = r >> 8;
            pk.h[j] = (__bf16)w[co * 2304 + c * 9 + k];
        }
        unsigned short* dst = reinterpret_cast<unsigned short*>(wq) + (size_t)e * 8;
        *reinterpret_cast<ushort4*>(dst)     = pk.u2[0];
        *reinterpret_cast<ushort4*>(dst + 4) = pk.u2[1];
    }
}

// ---- main: fused deformable implicit GEMM, BK=64, A-only LDS, B L2->reg ----
// (round-13 structure: the best-measured configuration, 44.5 us kernel)
// Block = 64 wo x 256 co, 512 threads / 8 waves (1M x 8N); wave slab 64(M) x 32(N)
// -> each wave's B fragments are UNIQUE (no cross-wave duplication), loaded
// directly from pre-permuted wq (L2-resident) into registers, double-buffered.
// LDS holds only the A tile (2 x 8KB) + meta: 34 KB. Per iter per wave:
// 8 ds_read_b128 (A) + 4 B reg-loads + 4 A-gathers + 16 MFMA.
// Wait ladder (FIFO: B(i+1)@s2, A(i+2)@s5): WAITV8 pre-MFMA0 drains B(i)
// (issued 1 iter ago); WAITV4 at combine drains A(i+1) (1 iter old), keeps
// B(i+1); pre-barrier lgkmcnt(0) only -- B(i+1)+A(i+2) cross the barrier.
__global__ __launch_bounds__(512, 1)
void deform_gemm_nhwc(const float* __restrict__ off, const __bf16* __restrict__ xh,
                      const __bf16* __restrict__ wq, float* __restrict__ out) {
    __shared__ float4 s_w[64 * 9];
    __shared__ int4   s_a[64 * 9];
    __shared__ unsigned short sA[2][64 * 64];    // [buf][p*64 + ch], XOR-swizzled

    const int tid  = threadIdx.x;
    const int lane = tid & 63;
    const int wv   = tid >> 6;               // 0..7 = N-eighth
    const int fr   = lane & 15;
    const int fq   = lane >> 4;

    const int bs = ((blockIdx.x & 7) << 5) | (blockIdx.x >> 3);  // bijective XCD swizzle
    const int b  = bs >> 6;
    const int ho = bs & 63;

    // ---- per-(k, p) bilinear metadata (9 taps x 64 positions) ----
    for (int i = tid; i < 576; i += 512) {
        const int k = i >> 6, p = i & 63;
        const int kh = k / 3, kw = k - kh * 3;
        const float dy = off[(((b * 18) + 2 * k    ) * 64 + ho) * 64 + p];
        const float dx = off[(((b * 18) + 2 * k + 1) * 64 + ho) * 64 + p];
        const float sy = (float)(ho - 1 + kh) + dy;
        const float sx = (float)(p  - 1 + kw) + dx;
        const float y0f = floorf(sy), x0f = floorf(sx);
        const float fy = sy - y0f, fx = sx - x0f;
        const int y0 = (int)y0f, x0 = (int)x0f;
        const int y1 = y0 + 1, x1 = x0 + 1;
        const bool vy0 = (unsigned)y0 < 64u, vy1 = (unsigned)y1 < 64u;
        const bool vx0 = (unsigned)x0 < 64u, vx1 = (unsigned)x1 < 64u;
        const int y0c = min(max(y0, 0), 63), y1c = min(max(y1, 0), 63);
        const int x0c = min(max(x0, 0), 63), x1c = min(max(x1, 0), 63);
        float4 wt;
        wt.x = (1.f - fy) * (1.f - fx) * ((vy0 & vx0) ? 1.f : 0.f);
        wt.y = (1.f - fy) * fx         * ((vy0 & vx1) ? 1.f : 0.f);
        wt.z = fy * (1.f - fx)         * ((vy1 & vx0) ? 1.f : 0.f);
        wt.w = fy * fx                 * ((vy1 & vx1) ? 1.f : 0.f);
        s_w[i] = wt;
        s_a[i] = make_int4((y0c << 6) + x0c, (y0c << 6) + x1c,
                           (y1c << 6) + x0c, (y1c << 6) + x1c);
    }

    f32x4 acc[4][2];
    #pragma unroll
    for (int mf = 0; mf < 4; ++mf)
        #pragma unroll
        for (int nf = 0; nf < 2; ++nf)
            acc[mf][nf] = (f32x4){0.f, 0.f, 0.f, 0.f};

    const __bf16* xb = xh + ((size_t)b << 20);
    // A-gen: 512 threads = 64 positions x 8 channel-octets (8 ch / thread / iter)
    const int p   = tid >> 3;                // 0..63
    const int oct = tid & 7;                 // c = oct*8 within the 64-ch iter block
    const int aw_off = (p << 6) + ((oct ^ (p & 7)) << 3);
    const char* base_lane = (const char*)xb + (oct << 4);

    // B fragment source for this wave: (i,wv) block at i*32768 + wv*4096 + lane*16
    const char* wqw = (const char*)wq + ((size_t)wv << 12) + (lane << 4);

    // A fragment read offsets (swizzled 16B units) for K32 halves
    const int ua0 = ((0 + fq) ^ (fr & 7)) << 3;
    const int ua1 = ((4 + fq) ^ (fr & 7)) << 3;

    __syncthreads();  // meta ready

    float4 wt_k;
    uint4 ga0, ga1, ga2, ga3;
    const char *aK0, *aK1, *aK2, *aK3;
    bf16x8 br[2][4];                         // B reg double buffer (static idx under unroll)

    {   // tap 0 meta
        wt_k = s_w[p];
        const int4 sa = s_a[p];
        aK0 = base_lane + ((size_t)sa.x << 9);
        aK1 = base_lane + ((size_t)sa.y << 9);
        aK2 = base_lane + ((size_t)sa.z << 9);
        aK3 = base_lane + ((size_t)sa.w << 9);
    }

    // ---- prologue: load B(0); gather+combine A(0); issue A(1) ----
    {
        #pragma unroll
        for (int f = 0; f < 4; ++f)
            br[0][f] = *reinterpret_cast<const bf16x8*>(wqw + f * 1024);
        ga0 = *reinterpret_cast<const uint4*>(aK0);
        ga1 = *reinterpret_cast<const uint4*>(aK1);
        ga2 = *reinterpret_cast<const uint4*>(aK2);
        ga3 = *reinterpret_cast<const uint4*>(aK3);
        WAITV0;
        {
            const unsigned* w0 = reinterpret_cast<const unsigned*>(&ga0);
            const unsigned* w1 = reinterpret_cast<const unsigned*>(&ga1);
            const unsigned* w2 = reinterpret_cast<const unsigned*>(&ga2);
            const unsigned* w3 = reinterpret_cast<const unsigned*>(&ga3);
            union { ushort8v u; __bf16 h[8]; } pk;
            #pragma unroll
            for (int j = 0; j < 8; ++j)
                pk.h[j] = (__bf16)(wt_k.x * c2f(w0[j >> 1], j & 1) + wt_k.y * c2f(w1[j >> 1], j & 1)
                                 + wt_k.z * c2f(w2[j >> 1], j & 1) + wt_k.w * c2f(w3[j >> 1], j & 1));
            *reinterpret_cast<ushort8v*>(&sA[0][aw_off]) = pk.u;
        }
        // issue A(1): same tap, channel block 1 (byte offset 128)
        ga0 = *reinterpret_cast<const uint4*>(aK0 + 128);
        ga1 = *reinterpret_cast<const uint4*>(aK1 + 128);
        ga2 = *reinterpret_cast<const uint4*>(aK2 + 128);
        ga3 = *reinterpret_cast<const uint4*>(aK3 + 128);
        SCHEDB;
        WAITLGKM0;
        __builtin_amdgcn_s_barrier();
        SCHEDB;
    }

    // ---- main loop: 36 iterations of BK=64 ----
    #pragma unroll 4
    for (int i = 0; i < NITER; ++i) {
        const unsigned short* sAc = sA[i & 1];

        // 1) A fragment reads (8 x ds_read_b128; rows mf*16+fr, two K-halves)
        bf16x8 a0[4], a1[4];
        #pragma unroll
        for (int mf = 0; mf < 4; ++mf) {
            const int ar = mf * 16 + fr;
            a0[mf] = *reinterpret_cast<const bf16x8*>(&sAc[(ar << 6) + ua0]);
            a1[mf] = *reinterpret_cast<const bf16x8*>(&sAc[(ar << 6) + ua1]);
        }

        // 2) B(i+1) reg loads (4 x dwordx4, coalesced, L2-resident, unique per wave)
        if (i < NITER - 1) {
            const char* bb = wqw + (size_t)(i + 1) * 32768;
            #pragma unroll
            for (int f = 0; f < 4; ++f)
                br[(i + 1) & 1][f] = *reinterpret_cast<const bf16x8*>(bb + f * 1024);
        }
        SCHEDB;

        // 3) drain B(i) (issued 1 iter ago), keep A(i+1)+B(i+1); MFMA K-half 0
        if (i == NITER - 1) { WAITV0; } else { WAITV8; }
        __builtin_amdgcn_s_setprio(1);
        #pragma unroll
        for (int mf = 0; mf < 4; ++mf)
            #pragma unroll
            for (int nf = 0; nf < 2; ++nf)
                acc[mf][nf] = __builtin_amdgcn_mfma_f32_16x16x32_bf16(a0[mf], br[i & 1][nf], acc[mf][nf], 0, 0, 0);
        __builtin_amdgcn_s_setprio(0);
        SCHEDB;

        // 4) combine A(i+1): drain A gathers (1 iter old), keep B(i+1); write sA
        if (i < NITER - 1) {
            WAITV4;
            unsigned short* sAn = const_cast<unsigned short*>(sA[(i + 1) & 1]);
            const unsigned* w0 = reinterpret_cast<const unsigned*>(&ga0);
            const unsigned* w1 = reinterpret_cast<const unsigned*>(&ga1);
            const unsigned* w2 = reinterpret_cast<const unsigned*>(&ga2);
            const unsigned* w3 = reinterpret_cast<const unsigned*>(&ga3);
            union { ushort8v u; __bf16 h[8]; } pk;
            #pragma unroll
            for (int j = 0; j < 8; ++j)
                pk.h[j] = (__bf16)(wt_k.x * c2f(w0[j >> 1], j & 1) + wt_k.y * c2f(w1[j >> 1], j & 1)
                                 + wt_k.z * c2f(w2[j >> 1], j & 1) + wt_k.w * c2f(w3[j >> 1], j & 1));
            *reinterpret_cast<ushort8v*>(&sAn[aw_off]) = pk.u;
        }
        SCHEDB;

        // 5) issue A(i+2) gathers; tap meta reload when (i+2)%4 == 0
        if (i < NITER - 2) {
            const int ia = i + 2;
            if ((ia & 3) == 0) {
                const int kk = ia >> 2;
                wt_k = s_w[(kk << 6) + p];
                const int4 sa = s_a[(kk << 6) + p];
                aK0 = base_lane + ((size_t)sa.x << 9);
                aK1 = base_lane + ((size_t)sa.y << 9);
                aK2 = base_lane + ((size_t)sa.z << 9);
                aK3 = base_lane + ((size_t)sa.w << 9);
            }
            const int cb = (ia & 3) << 7;    // channel-block byte offset within the tap
            ga0 = *reinterpret_cast<const uint4*>(aK0 + cb);
            ga1 = *reinterpret_cast<const uint4*>(aK1 + cb);
            ga2 = *reinterpret_cast<const uint4*>(aK2 + cb);
            ga3 = *reinterpret_cast<const uint4*>(aK3 + cb);
        }
        SCHEDB;

        // 6) MFMA K-half 1 (B(i) half1 already in regs)
        __builtin_amdgcn_s_setprio(1);
        #pragma unroll
        for (int mf = 0; mf < 4; ++mf)
            #pragma unroll
            for (int nf = 0; nf < 2; ++nf)
                acc[mf][nf] = __builtin_amdgcn_mfma_f32_16x16x32_bf16(a1[mf], br[i & 1][2 + nf], acc[mf][nf], 0, 0, 0);
        __builtin_amdgcn_s_setprio(0);

        // 7) pre-barrier: drain only ds ops; B(i+1)x4 and A(i+2)x4 cross the barrier
        WAITLGKM0;
        __builtin_amdgcn_s_barrier();
        SCHEDB;
    }

    // ---- epilogue: rows m = mf*16 + fq*4 + j, cols n = wv*32 + nf*16 + fr ----
    float* ob = out + (size_t)b * (256 * 4096) + (ho << 6);
    #pragma unroll
    for (int nf = 0; nf < 2; ++nf) {
        const int n = (wv << 5) + nf * 16 + fr;
        #pragma unroll
        for (int mf = 0; mf < 4; ++mf) {
            const int m = mf * 16 + (fq << 2);
            *reinterpret_cast<f32x4*>(&ob[(size_t)n * 4096 + m]) = acc[mf][nf];
        }
    }
}

// ---- fallback (ws too small): convert-on-the-fly weights, NCHW gathers ----
__global__ __launch_bounds__(256, 2)
void deform_gemm_fb(const float* __restrict__ x, const float* __restrict__ off,
                    const float* __restrict__ wf, float* __restrict__ out) {
    __shared__ float4 s_w[32 * 9];
    __shared__ int4   s_a[32 * 9];
    __shared__ unsigned short sA[2][32 * 32];
    __shared__ unsigned short sB[2][256 * 32];

    const int tid  = threadIdx.x;
    const int lane = tid & 63;
    const int wv   = tid >> 6;
    const int fr   = lane & 15;
    const int fq   = lane >> 4;
    const int bs  = ((blockIdx.x & 7) << 6) | (blockIdx.x >> 3);
    const int b   = bs >> 7;
    const int ho  = (bs >> 1) & 63;
    const int wo0 = (bs & 1) << 5;

    for (int i = tid; i < 32 * 9; i += 256) {
        const int k = i >> 5, p = i & 31, wo = wo0 + p;
        const int kh = k / 3, kw = k - kh * 3;
        const float dy = off[(((b * 18) + 2 * k    ) * 64 + ho) * 64 + wo];
        const float dx = off[(((b * 18) + 2 * k + 1) * 64 + ho) * 64 + wo];
        const float sy = (float)(ho - 1 + kh) + dy;
        const float sx = (float)(wo - 1 + kw) + dx;
        const float y0f = floorf(sy), x0f = floorf(sx);
        const float fy = sy - y0f, fx = sx - x0f;
        const int y0 = (int)y0f, x0 = (int)x0f;
        const int y1 = y0 + 1, x1 = x0 + 1;
        const bool vy0 = (unsigned)y0 < 64u, vy1 = (unsigned)y1 < 64u;
        const bool vx0 = (unsigned)x0 < 64u, vx1 = (unsigned)x1 < 64u;
        const int y0c = min(max(y0, 0), 63), y1c = min(max(y1, 0), 63);
        const int x0c = min(max(x0, 0), 63), x1c = min(max(x1, 0), 63);
        float4 wt;
        wt.x = (1.f - fy) * (1.f - fx) * ((vy0 & vx0) ? 1.f : 0.f);
        wt.y = (1.f - fy) * fx         * ((vy0 & vx1) ? 1.f : 0.f);
        wt.z = fy * (1.f - fx)         * ((vy1 & vx0) ? 1.f : 0.f);
        wt.w = fy * fx                 * ((vy1 & vx1) ? 1.f : 0.f);
        s_w[i] = wt;
        s_a[i] = make_int4((y0c << 6) + x0c, (y0c << 6) + x1c,
                           (y1c << 6) + x0c, (y1c << 6) + x1c);
    }

    f32x4 acc[2][4];
    #pragma unroll
    for (int mf = 0; mf < 2; ++mf)
        #pragma unroll
        for (int nf = 0; nf < 4; ++nf)
            acc[mf][nf] = (f32x4){0.f, 0.f, 0.f, 0.f};

    const float* xb = x + (size_t)b * (256 * 4096);
    const int p  = tid & 31;
    const int rq = tid >> 5;
    const int aw_off = (p << 5) + ((((rq >> 1) ^ ((p >> 1) & 3)) << 3)) + ((rq & 1) << 2);

    int brow[4], bcol[4];
    #pragma unroll
    for (int q = 0; q < 4; ++q) {
        brow[q] = (wv << 6) + (q << 4) + (lane >> 2);
        bcol[q] = ((lane & 3) ^ ((brow[q] >> 1) & 3)) << 3;
    }
    const int bphys = (lane & 3) << 3;

    __syncthreads();

    for (int t = 0; t < 72; ++t) {
        const int cur = t & 1;
        const int r0 = t * 32;
        union { ushort4 u; __bf16 h[4]; } pk;
        #pragma unroll
        for (int j = 0; j < 4; ++j) {
            const int r = r0 + rq * 4 + j;
            const int c = r / 9, k = r - c * 9;
            const float4 wt = s_w[(k << 5) + p];
            const int4 ad = s_a[(k << 5) + p];
            const float* xp = xb + (c << 12);
            pk.h[j] = (__bf16)(wt.x * xp[ad.x] + wt.y * xp[ad.y]
                             + wt.z * xp[ad.z] + wt.w * xp[ad.w]);
        }
        *reinterpret_cast<ushort4*>(&sA[cur][aw_off]) = pk.u;
        #pragma unroll
        for (int q = 0; q < 4; ++q) {
            const float4* s = reinterpret_cast<const float4*>(wf + (size_t)brow[q] * RTOT + r0 + bcol[q]);
            float4 f0 = s[0], f1 = s[1];
            union { uint4 u; __bf16 h[8]; } ub;
            ub.h[0]=(__bf16)f0.x; ub.h[1]=(__bf16)f0.y; ub.h[2]=(__bf16)f0.z; ub.h[3]=(__bf16)f0.w;
            ub.h[4]=(__bf16)f1.x; ub.h[5]=(__bf16)f1.y; ub.h[6]=(__bf16)f1.z; ub.h[7]=(__bf16)f1.w;
            *reinterpret_cast<uint4*>(&sB[cur][(brow[q] << 5) + bphys]) = ub.u;
        }
        __syncthreads();
        bf16x8 af[2], bfr[4];
        #pragma unroll
        for (int mf = 0; mf < 2; ++mf) {
            const int row = mf * 16 + fr;
            af[mf] = *reinterpret_cast<const bf16x8*>(&sA[cur][(row << 5) + ((fq ^ ((row >> 1) & 3)) << 3)]);
        }
        #pragma unroll
        for (int nf = 0; nf < 4; ++nf) {
            const int row = (wv << 6) + nf * 16 + fr;
            bfr[nf] = *reinterpret_cast<const bf16x8*>(&sB[cur][(row << 5) + ((fq ^ ((row >> 1) & 3)) << 3)]);
        }
        #pragma unroll
        for (int mf = 0; mf < 2; ++mf)
            #pragma unroll
            for (int nf = 0; nf < 4; ++nf)
                acc[mf][nf] = __builtin_amdgcn_mfma_f32_16x16x32_bf16(af[mf], bfr[nf], acc[mf][nf], 0, 0, 0);
        __syncthreads();
    }

    float* ob = out + (size_t)b * (256 * 4096) + (ho << 6) + wo0;
    #pragma unroll
    for (int nf = 0; nf < 4; ++nf) {
        const int n = (wv << 6) + nf * 16 + fr;
        #pragma unroll
        for (int mf = 0; mf < 2; ++mf) {
            const int m = mf * 16 + (fq << 2);
            *reinterpret_cast<f32x4*>(&ob[(size_t)n * 4096 + m]) = acc[mf][nf];
        }
    }
}

extern "C" void kernel_launch(void* const* d_in, const int* in_sizes, int n_in,
                              void* d_out, int out_size, void* d_ws, size_t ws_size,
                              hipStream_t stream) {
    const float* x   = (const float*)d_in[0];
    const float* off = (const float*)d_in[1];
    const float* w   = (const float*)d_in[2];
    float* out = (float*)d_out;

    const size_t xh_bytes = (size_t)4 * 64 * 64 * 256 * sizeof(__bf16);   // 8.4 MB
    const size_t wq_bytes = (size_t)NITER * 8 * 4 * 64 * 16;              // 1.18 MB
    if (ws_size >= xh_bytes + wq_bytes) {
        __bf16* xh = (__bf16*)d_ws;
        __bf16* wq = (__bf16*)((char*)d_ws + xh_bytes);
        prep_merged<<<dim3(544), dim3(256), 0, stream>>>(x, xh, w, wq);
        deform_gemm_nhwc<<<dim3(256), dim3(512), 0, stream>>>(off, xh, wq, out);
    } else {
        deform_gemm_fb<<<dim3(512), dim3(256), 0, stream>>>(x, off, w, out);
    }
}